// Round 1
// baseline (161.238 us; speedup 1.0000x reference)
//
#include <hip/hip_runtime.h>

// Problem constants (from reference): B=32, H=512, W=512, P=100000
#define W_ 512
#define HWIMG (512 * 512)
#define P_ 100000
#define NTOT 3200000      // B*P
#define NVEC 800000       // NTOT/4  (P%4==0 so a vec4 group never crosses batch)
#define NBLK 3125         // NVEC/256 exactly

__global__ void rdl_zero_kernel(float* out) {
    if (threadIdx.x == 0) out[0] = 0.0f;
}

__global__ __launch_bounds__(256) void rdl_kernel(
    const float* __restrict__ img,
    const int*  __restrict__ xA, const int* __restrict__ yA,
    const int*  __restrict__ xB, const int* __restrict__ yB,
    const int*  __restrict__ ordn,
    float* __restrict__ out)
{
    const int v = blockIdx.x * blockDim.x + threadIdx.x;   // 0 .. NVEC-1 (exact fit)

    // vectorized dwordx4 loads of the 5 index streams
    const int4 xa4 = reinterpret_cast<const int4*>(xA)[v];
    const int4 ya4 = reinterpret_cast<const int4*>(yA)[v];
    const int4 xb4 = reinterpret_cast<const int4*>(xB)[v];
    const int4 yb4 = reinterpret_cast<const int4*>(yB)[v];
    const int4 od4 = reinterpret_cast<const int4*>(ordn)[v];

    const int i0 = v * 4;
    const int b  = i0 / P_;                 // whole group shares batch index
    const float* imb = img + (size_t)b * HWIMG;

    const int xa[4] = {xa4.x, xa4.y, xa4.z, xa4.w};
    const int ya[4] = {ya4.x, ya4.y, ya4.z, ya4.w};
    const int xb[4] = {xb4.x, xb4.y, xb4.z, xb4.w};
    const int yb[4] = {yb4.x, yb4.y, yb4.z, yb4.w};
    const int od[4] = {od4.x, od4.y, od4.z, od4.w};

    float acc = 0.0f;
#pragma unroll
    for (int j = 0; j < 4; ++j) {
        const float zA = imb[ya[j] * W_ + xa[j]];
        const float zB = imb[yb[j] * W_ + xb[j]];
        const float d  = zA - zB;
        const float gt = (float)(od[j] - 1);          // in {-1, 0, 1}
        const float t  = -gt * d;
        // stable softplus: log1p(exp(t)) = max(t,0) + log1p(exp(-|t|))
        const float sp = fmaxf(t, 0.0f) + log1pf(expf(-fabsf(t)));
        acc += (od[j] != 1) ? sp : d * d;             // mask in {0,1}
    }

    // wave-64 shuffle reduction
#pragma unroll
    for (int off = 32; off > 0; off >>= 1)
        acc += __shfl_down(acc, off, 64);

    __shared__ float ws[4];
    const int lane = threadIdx.x & 63;
    const int wid  = threadIdx.x >> 6;
    if (lane == 0) ws[wid] = acc;
    __syncthreads();
    if (threadIdx.x == 0) {
        const float s = ws[0] + ws[1] + ws[2] + ws[3];
        atomicAdd(out, s * (1.0f / (float)NTOT));
    }
}

extern "C" void kernel_launch(void* const* d_in, const int* in_sizes, int n_in,
                              void* d_out, int out_size, void* d_ws, size_t ws_size,
                              hipStream_t stream) {
    const float* img = (const float*)d_in[0];
    const int*   xA  = (const int*)d_in[1];
    const int*   yA  = (const int*)d_in[2];
    const int*   xB  = (const int*)d_in[3];
    const int*   yB  = (const int*)d_in[4];
    const int*   od  = (const int*)d_in[5];
    float* out = (float*)d_out;

    rdl_zero_kernel<<<1, 64, 0, stream>>>(out);
    rdl_kernel<<<NBLK, 256, 0, stream>>>(img, xA, yA, xB, yB, od, out);
}